// Round 6
// baseline (754.348 us; speedup 1.0000x reference)
//
#include <hip/hip_runtime.h>

// SNG: sn[b,l] = 8-step majority chain (reference scan unrolled):
//   v_0 = 0; v_{i+1} = maj(x[b,i], v_i, r[b,i,l+i]); sn[b,l] = v_8
// maj(1,v,r) = v|r ; maj(0,v,r) = v&r  -> block-uniform branch per row.
//
// v5 (re-run; round-5 bench was lost to GPUAcquisitionTimeout):
// every global load is a 16B-aligned dwordx4. Thread owns 16 consecutive
// outputs [l, l+16); for row i it loads 5 aligned int4s at l + 4*(i>>2) + 16B*k
// and selects dwords statically at s = i&3 (compile-time -> register renaming,
// zero shift cost). Rows before ctz(nb) are skipped: v stays 0 through them.

#define BATCH 1024
#define PBITS 8
#define LBITS 16384
#define TLEN (PBITS + LBITS)   // 16392 dwords per r-row; 16392 % 4 == 0

typedef int v4i __attribute__((ext_vector_type(4)));

__global__ __launch_bounds__(256) void sng_kernel(const int* __restrict__ num,
                                                  const int* __restrict__ r,
                                                  int* __restrict__ out) {
    const int t = threadIdx.x;                  // 0..255
    const int b = blockIdx.x >> 2;              // 4 blocks per batch row
    const int jb = (blockIdx.x & 3) << 12;      // chunk base dword within row
    const int l = jb + (t << 4);                // first of 16 owned outputs; l%16==0

    const int nb = num[b];                      // wave-uniform -> SGPR
    const int start = __builtin_ctz(nb | (1 << PBITS));  // first x=1 row (8 if nb==0)

    const int* rb = r + (size_t)b * (PBITS * TLEN) + l;

    int v[16];
#pragma unroll
    for (int k = 0; k < 16; ++k) v[k] = 0;

#pragma unroll
    for (int i = 0; i < PBITS; ++i) {
        if (i < start) continue;                // block-uniform scalar branch
        // aligned window [l + 4*(i>>2), +20) covers needed [l+i, l+i+16)
        const int* p = rb + (size_t)i * TLEN + 4 * (i >> 2);
        int a[20];
#pragma unroll
        for (int q = 0; q < 5; ++q) {
            const v4i w = __builtin_nontemporal_load(
                reinterpret_cast<const v4i*>(p + 4 * q));   // 16B-aligned
            a[4 * q + 0] = w.x; a[4 * q + 1] = w.y;
            a[4 * q + 2] = w.z; a[4 * q + 3] = w.w;
        }
        const int s = i & 3;                    // compile-time per unrolled row
        if ((nb >> i) & 1) {
#pragma unroll
            for (int k = 0; k < 16; ++k) v[k] |= a[s + k];  // static idx -> regs
        } else {
#pragma unroll
            for (int k = 0; k < 16; ++k) v[k] &= a[s + k];
        }
    }

    int* o = out + (size_t)b * LBITS + l;       // 16 consecutive dwords, 16B-aligned
#pragma unroll
    for (int q = 0; q < 4; ++q) {
        v4i w;
        w.x = v[4 * q + 0]; w.y = v[4 * q + 1];
        w.z = v[4 * q + 2]; w.w = v[4 * q + 3];
        __builtin_nontemporal_store(w, reinterpret_cast<v4i*>(o + 4 * q));
    }
}

extern "C" void kernel_launch(void* const* d_in, const int* in_sizes, int n_in,
                              void* d_out, int out_size, void* d_ws, size_t ws_size,
                              hipStream_t stream) {
    const int* num = (const int*)d_in[0];   // [B] int32
    const int* r   = (const int*)d_in[1];   // [B, P, P+L] int32 (0/1)
    int* out = (int*)d_out;                 // [B, L] int32 (0/1)

    const int blocks = BATCH * 4;           // 4096 blocks x 256 thr, 16 out/thread
    sng_kernel<<<blocks, 256, 0, stream>>>(num, r, out);
}

// Round 8
// 684.673 us; speedup vs baseline: 1.1018x; 1.1018x over previous
//
#include <hip/hip_runtime.h>

// SNG: sn[b,l] = 8-step majority chain (reference scan unrolled):
//   v_0 = 0; v_{i+1} = maj(x[b,i], v_i, r[b,i,l+i]); sn[b,l] = v_8
// maj(1,v,r) = v|r ; maj(0,v,r) = v&r  -> block-uniform branch per row.
//
// v7 (re-run; rounds 5 and 7 both lost to GPUAcquisitionTimeout):
// aligned + lane-contiguous + minimal traffic.
//  - rows with shift i%4 != 0 are staged into LDS with 16B-aligned
//    global_load_lds dwordx4 (each instruction = contiguous 4KB wave burst);
//    the +i shift is absorbed by the LDS read index (lane stride 1 dword ->
//    2-way bank aliasing, free). ONE __syncthreads total (v4's mistake: 16).
//  - rows 0,4 (shift 0 mod 4) bypass LDS: direct dword loads, lanes contiguous.
//  - rows before ctz(num) skipped entirely (v stays 0): ~12% read savings.

#define BATCH 1024
#define PBITS 8
#define LBITS 16384
#define TLEN (PBITS + LBITS)   // 16392 dwords per r-row; 16392 % 4 == 0

typedef const __attribute__((address_space(1))) void gvoid;
typedef __attribute__((address_space(3))) void lvoid;

__global__ __launch_bounds__(256, 4) void sng_kernel(const int* __restrict__ num,
                                                     const int* __restrict__ r,
                                                     int* __restrict__ out) {
    __shared__ int lds[6][1032];               // 24,768 B -> 6 blocks/CU

    const int t = threadIdx.x;                 // 0..255
    const int b = blockIdx.x >> 4;             // 16 blocks per batch row
    const int jb = (blockIdx.x & 15) << 10;    // 1024-dword chunk base

    const int nb = num[b];                     // wave-uniform -> SGPR
    const int start = __builtin_ctz(nb | 256); // first participating row (8 if nb==0)

    const int* rb = r + (size_t)b * (PBITS * TLEN) + jb;

    // ---- stage shifted rows (i%4!=0) into LDS; all async, aligned, contiguous
#pragma unroll
    for (int i = 0; i < PBITS; ++i) {
        if ((i & 3) == 0) continue;            // rows 0,4 go direct
        if (i >= start) {                      // block-uniform scalar branch
            const int si = (i < 4) ? (i - 1) : (i - 2);   // 1,2,3,5,6,7 -> 0..5
            const int* src = rb + (size_t)i * TLEN;       // 16B-aligned
            __builtin_amdgcn_global_load_lds((gvoid*)(src + 4 * t),
                                             (lvoid*)(&lds[si][4 * t]), 16, 0, 0);
            if (t < 2)                         // tail dwords 1024..1031 (window +7)
                __builtin_amdgcn_global_load_lds((gvoid*)(src + 1024 + 4 * t),
                                                 (lvoid*)(&lds[si][1024 + 4 * t]),
                                                 16, 0, 0);
        }
    }

    // ---- rows 0,4: direct loads, per-lane dword, lanes contiguous (1KB/instr)
    int d0[4], d4[4];
    if (start == 0) {
#pragma unroll
        for (int k = 0; k < 4; ++k)
            d0[k] = __builtin_nontemporal_load(rb + t + 256 * k);
    }
    if (start <= 4) {
#pragma unroll
        for (int k = 0; k < 4; ++k)
            d4[k] = __builtin_nontemporal_load(rb + (size_t)4 * TLEN + 4 + t + 256 * k);
    }

    __syncthreads();                           // single barrier: drains vmcnt(0)

    // ---- combine: thread owns output dwords jb + t + 256k, k=0..3
    int v[4] = {0, 0, 0, 0};
#pragma unroll
    for (int i = 0; i < PBITS; ++i) {
        if (i < start) continue;               // block-uniform
        int a[4];
        if (i == 0) {
#pragma unroll
            for (int k = 0; k < 4; ++k) a[k] = d0[k];
        } else if (i == 4) {
#pragma unroll
            for (int k = 0; k < 4; ++k) a[k] = d4[k];
        } else {
            const int si = (i < 4) ? (i - 1) : (i - 2);
#pragma unroll
            for (int k = 0; k < 4; ++k)
                a[k] = lds[si][t + i + 256 * k];   // lane stride 1 -> conflict-free
        }
        if ((nb >> i) & 1) {
#pragma unroll
            for (int k = 0; k < 4; ++k) v[k] |= a[k];
        } else {
#pragma unroll
            for (int k = 0; k < 4; ++k) v[k] &= a[k];
        }
    }

    int* o = out + (size_t)b * LBITS + jb + t;
#pragma unroll
    for (int k = 0; k < 4; ++k)
        __builtin_nontemporal_store(v[k], o + 256 * k);   // contiguous 1KB/instr
}

extern "C" void kernel_launch(void* const* d_in, const int* in_sizes, int n_in,
                              void* d_out, int out_size, void* d_ws, size_t ws_size,
                              hipStream_t stream) {
    const int* num = (const int*)d_in[0];   // [B] int32
    const int* r   = (const int*)d_in[1];   // [B, P, P+L] int32 (0/1)
    int* out = (int*)d_out;                 // [B, L] int32 (0/1)

    const int blocks = BATCH * 16;          // 16384 blocks x 256 thr, 4 out/thread
    sng_kernel<<<blocks, 256, 0, stream>>>(num, r, out);
}

// Round 9
// 669.092 us; speedup vs baseline: 1.1274x; 1.0233x over previous
//
#include <hip/hip_runtime.h>

// SNG: sn[b,l] = 8-step majority chain (reference scan unrolled):
//   v_0 = 0; v_{i+1} = maj(x[b,i], v_i, r[b,i,l+i]); sn[b,l] = v_8
// maj(1,v,r) = v|r ; maj(0,v,r) = v&r.
//
// v8 = v3 (best: 670.8) + two pure-subtraction levers, memory pattern of
// surviving rows byte-identical to v3:
//  - leading-row skip: rows i < ctz(nb) leave v=0 -> loads skipped entirely
//    (block-uniform scalar branch; E[skip] ~ 1 row = 12.5% of read traffic)
//  - uniform-branch combine: (nb>>i)&1 is block-uniform -> single v_or/v_and
//    per element instead of 4-op MAJ (75% less combine VALU)

#define BATCH 1024
#define PBITS 8
#define LBITS 16384
#define TLEN (PBITS + LBITS)   // 16392 dwords per r-row

typedef int v4i __attribute__((ext_vector_type(4)));

__global__ __launch_bounds__(256) void sng_kernel(const int* __restrict__ num,
                                                  const int* __restrict__ r,
                                                  int* __restrict__ out) {
    const int t = threadIdx.x;                 // 0..255
    const int b = blockIdx.x >> 2;             // 4 blocks per batch row
    const int jb = (blockIdx.x & 3) << 12;     // dword base within row

    const int nb = num[b];                     // wave-uniform -> SGPR
    const int start = __builtin_ctz(nb | 256); // first relevant row (8 if nb==0)

    // per-thread base: batch row + chunk + own 16B slot (v3 mapping)
    const int* rb = r + (size_t)b * (PBITS * TLEN) + jb + (t << 2);

    v4i v0 = {0,0,0,0}, v1 = {0,0,0,0}, v2 = {0,0,0,0}, v3 = {0,0,0,0};

#pragma unroll
    for (int i = 0; i < PBITS; ++i) {
        if (i < start) continue;               // block-uniform scalar skip
        const int* rp = rb + i * TLEN + i;     // diagonal shift +i (4B-aligned, as v3)
        const v4i a0 = __builtin_nontemporal_load(reinterpret_cast<const v4i*>(rp));
        const v4i a1 = __builtin_nontemporal_load(reinterpret_cast<const v4i*>(rp + 1024));
        const v4i a2 = __builtin_nontemporal_load(reinterpret_cast<const v4i*>(rp + 2048));
        const v4i a3 = __builtin_nontemporal_load(reinterpret_cast<const v4i*>(rp + 3072));
        if ((nb >> i) & 1) {                   // block-uniform: OR row
            v0 |= a0; v1 |= a1; v2 |= a2; v3 |= a3;
        } else {                               // AND row
            v0 &= a0; v1 &= a1; v2 &= a2; v3 &= a3;
        }
    }

    // out int4 index: block covers 1024 int4s; thread t owns t + 256k (v3 mapping)
    v4i* o = reinterpret_cast<v4i*>(out) + ((blockIdx.x << 10) | t);
    __builtin_nontemporal_store(v0, o);
    __builtin_nontemporal_store(v1, o + 256);
    __builtin_nontemporal_store(v2, o + 512);
    __builtin_nontemporal_store(v3, o + 768);
}

extern "C" void kernel_launch(void* const* d_in, const int* in_sizes, int n_in,
                              void* d_out, int out_size, void* d_ws, size_t ws_size,
                              hipStream_t stream) {
    const int* num = (const int*)d_in[0];   // [B] int32
    const int* r   = (const int*)d_in[1];   // [B, P, P+L] int32 (0/1)
    int* out = (int*)d_out;                 // [B, L] int32 (0/1)

    const int blocks = BATCH * 4;           // 4096 blocks x 256 thr, 16 out/thread
    sng_kernel<<<blocks, 256, 0, stream>>>(num, r, out);
}